// Round 5
// baseline (1103.717 us; speedup 1.0000x reference)
//
#include <hip/hip_runtime.h>
#include <math.h>

#define B_TOTAL  262144
#define ROWS     64
#define NWG      (B_TOTAL/ROWS)   // 4096
#define NTHR     512
#define PI_F     3.14159265358979323846f
#define NORM_R   (500.0f/150000.0f)

typedef float  f32x4  __attribute__((ext_vector_type(4)));
typedef short  bf16x8 __attribute__((ext_vector_type(8)));

// ---- bf16 weight workspace layout (ushort units) ----
#define SRZ 352   // [512][352]: k<73 = W_ih rows 0..511 ; k 96..351 = W_hh rows 0..511
#define SNI 96    // [256][96]:  W_ih rows 512..767 (n-gate input), k>=73 zero
#define SNH 256   // [256][256]: W_hh rows 512..767
#define SW1 256
#define SW2 256
#define SW3 128   // [256][128]: rows >=162 zero
#define OFF_RZ 0
#define OFF_NI (OFF_RZ + 512*SRZ)
#define OFF_NH (OFF_NI + 256*SNI)
#define OFF_W1 (OFF_NH + 256*SNH)
#define OFF_W2 (OFF_W1 + 256*SW1)
#define OFF_W3 (OFF_W2 + 128*SW2)
#define W_TOTAL (OFF_W3 + 256*SW3)  // 401408 ushort = 784 KiB

// ---- LDS layout (byte offsets), ROWS=64 ----
#define RSTRIDE 104
#define LDS_HB   (ROWS*RSTRIDE*2)          // Rb: [64][104] bf16           13312
#define LDS_F1   (LDS_HB + ROWS*256*2)     // Hb: [64][256] bf16 swizzled  32768
#define LDS_STG  (LDS_F1 + ROWS*256*2)     // F1: [64][256] bf16 swizzled  32768 (also input scratch)
#define LDS_XMC  (LDS_STG + 4*16384)       // STG: 4 x 16KB slice quad-buffer
#define LDS_TOTAL (LDS_XMC + ROWS*6*4)     // xmc: [64][6] f32  => 145920 B (1 WG/CU)

#define WAIT_VM4 asm volatile("s_waitcnt vmcnt(4)" ::: "memory")
#define WAIT_VM2 asm volatile("s_waitcnt vmcnt(2)" ::: "memory")
#define WAIT_VM0 asm volatile("s_waitcnt vmcnt(0)" ::: "memory")
#define BARv     __builtin_amdgcn_s_barrier()
#define N_SLICES 49

__device__ __forceinline__ ushort f2bf(float f){
    union { float f; unsigned u; } v; v.f = f;
    unsigned r = v.u + 0x7FFFu + ((v.u >> 16) & 1u);
    return (ushort)(r >> 16);
}
__device__ __forceinline__ float b2f(ushort u){
    union { unsigned u; float f; } v; v.u = ((unsigned)u) << 16;
    return v.f;
}
__device__ __forceinline__ float sigm(float x){ return 1.0f/(1.0f+__expf(-x)); }
__device__ __forceinline__ float tanh_(float x){ return 1.0f - 2.0f/(__expf(2.0f*x)+1.0f); }
__device__ __forceinline__ int swzb(int row, int k){          // [*][256] bf16, 16B-XOR swizzle
    return ((row<<9) + (k<<1)) ^ ((row&7)<<4);
}

// stage a 16KB slice: 256 cols x 64B (32 k-elems), XOR-swizzled k-chunks.
__device__ __forceinline__ void stageA(const ushort* pb, int stride, int koff,
                                       char* dst, int w, int lane) {
    #pragma unroll
    for (int i = 0; i < 2; ++i) {
        int idx  = (w*2 + i)*64 + lane;        // 0..1023
        int col  = idx >> 2;
        int kq   = (idx & 3) ^ ((col >> 1) & 3);
        const ushort* g = pb + (size_t)col*stride + koff + kq*8;
        __builtin_amdgcn_global_load_lds(
            (const __attribute__((address_space(1))) void*)g,
            (__attribute__((address_space(3))) void*)(dst + (w*2+i)*1024),
            16, 0, 0);
    }
}
// stage a 16KB slice: 128 cols x 128B (64 k-elems)
__device__ __forceinline__ void stageB(const ushort* pb, int stride, int koff,
                                       char* dst, int w, int lane) {
    #pragma unroll
    for (int i = 0; i < 2; ++i) {
        int idx  = (w*2 + i)*64 + lane;
        int col  = idx >> 3;
        int kq   = (idx & 7) ^ (col & 7);
        const ushort* g = pb + (size_t)col*stride + koff + kq*8;
        __builtin_amdgcn_global_load_lds(
            (const __attribute__((address_space(1))) void*)g,
            (__attribute__((address_space(3))) void*)(dst + (w*2+i)*1024),
            16, 0, 0);
    }
}
__device__ __forceinline__ bf16x8 rdA16(const char* sb, int col, int lk){
    int slot = lk ^ ((col >> 1) & 3);
    return *(const bf16x8*)(sb + col*64 + slot*16);
}
__device__ __forceinline__ bf16x8 rdB16(const char* sb, int col, int ksub, int lk){
    int slot = ((ksub<<2)|lk) ^ (col & 7);
    return *(const bf16x8*)(sb + col*128 + slot*16);
}

// unified slice-descriptor staging (wave-uniform branches)
__device__ __forceinline__ void stage_k(const ushort* ws, int k, char* STG, int w, int lane){
    char* dst = STG + ((k & 3) << 14);
    if (k < 11)      stageA(ws + OFF_RZ,                   SRZ, k*32,      dst, w, lane);
    else if (k < 22) stageA(ws + OFF_RZ + (size_t)256*SRZ, SRZ, (k-11)*32, dst, w, lane);
    else if (k < 25) stageA(ws + OFF_NI,                   SNI, (k-22)*32, dst, w, lane);
    else if (k < 33) stageA(ws + OFF_NH,                   SNH, (k-25)*32, dst, w, lane);
    else if (k < 41) stageA(ws + OFF_W1,                   SW1, (k-33)*32, dst, w, lane);
    else if (k < 45) stageB(ws + OFF_W2,                   SW2, (k-41)*64, dst, w, lane);
    else             stageA(ws + OFF_W3,                   SW3, (k-45)*32, dst, w, lane);
}

#define SLICE_PRE(kk) do { \
    if ((kk) < N_SLICES-2)      WAIT_VM4; \
    else if ((kk) == N_SLICES-2) WAIT_VM2; \
    else                         WAIT_VM0; \
    BARv; \
    if ((kk)+3 < N_SLICES) stage_k(ws, (kk)+3, STG, w, lane); \
} while(0)

#define MM8(ACC) do { _Pragma("unroll") \
    for (int j = 0; j < 4; ++j) { \
        bf16x8 b = rdA16(sb, nq*64 + j*16 + lr, lk); \
        ACC[0][j] = __builtin_amdgcn_mfma_f32_16x16x32_bf16(a0, b, ACC[0][j], 0,0,0); \
        ACC[1][j] = __builtin_amdgcn_mfma_f32_16x16x32_bf16(a1, b, ACC[1][j], 0,0,0); \
    } } while(0)

__global__ void prep_weights(const float* __restrict__ W_ih, const float* __restrict__ W_hh,
                             const float* __restrict__ W1, const float* __restrict__ W2,
                             const float* __restrict__ W3, ushort* __restrict__ ws)
{
    int id = blockIdx.x*256 + threadIdx.x;
    if (id >= W_TOTAL) return;
    float v = 0.0f;
    if (id < OFF_NI) {
        int t = id; int n = t / SRZ, k = t - n*SRZ;
        if (k < 73) v = W_ih[n*73 + k];
        else if (k >= 96) v = W_hh[n*256 + (k-96)];
    } else if (id < OFF_NH) {
        int t = id - OFF_NI; int n = t / SNI, k = t - n*SNI;
        if (k < 73) v = W_ih[(512+n)*73 + k];
    } else if (id < OFF_W1) {
        int t = id - OFF_NH; int n = t >> 8, k = t & 255;
        v = W_hh[(512+n)*256 + k];
    } else if (id < OFF_W2) {
        int t = id - OFF_W1; int n = t >> 8, k = t & 255;
        v = W1[n*256 + k];
    } else if (id < OFF_W3) {
        int t = id - OFF_W2; int n = t >> 8, k = t & 255;
        v = W2[n*256 + k];
    } else {
        int t = id - OFF_W3; int n = t >> 7, k = t & 127;
        if (n < 162) v = W3[n*128 + k];
    }
    ws[id] = f2bf(v);
}

__global__ __launch_bounds__(NTHR, 2) void knet_mfma(
    const float* __restrict__ meas, const float* __restrict__ mask,
    const float* __restrict__ dt,   const float* __restrict__ baselines,
    const float* __restrict__ x_prev, const float* __restrict__ hx,
    const float* __restrict__ b_ih, const float* __restrict__ b_hh,
    const float* __restrict__ ln_g, const float* __restrict__ ln_b,
    const float* __restrict__ b1,   const float* __restrict__ b2,
    const float* __restrict__ b3,
    const ushort* __restrict__ ws,
    float* __restrict__ out)
{
    extern __shared__ char smem[];
    ushort* Rb  = (ushort*)smem;
    char*   Hb  = smem + LDS_HB;
    char*   F1  = smem + LDS_F1;
    char*   STG = smem + LDS_STG;
    float*  xmc = (float*)(smem + LDS_XMC);

    const int tid  = threadIdx.x;
    const int w    = __builtin_amdgcn_readfirstlane(tid >> 6);
    const int nq   = w & 3;
    const int mh   = w >> 2;
    const int lane = tid & 63;
    const int lr   = lane & 15;
    const int lk   = lane >> 4;
    const int lk8  = lk * 8;
    const int row0 = blockIdx.x * ROWS;
    const int mrow = mh*32 + lr;
    float* hout = out + (size_t)B_TOTAL*6;

    // prologue: 3 slices in flight before anything else
    stage_k(ws, 0, STG, w, lane);
    stage_k(ws, 1, STG, w, lane);
    stage_k(ws, 2, STG, w, lane);

    // ====== coalesced input staging -> F1 scratch (f32) ======
    // layout: meas[64*27]@0  mask@1728  baselines[64*12]@3456  x_prev[64*6]@4224  dt[64]@4608
    float* scr = (float*)F1;
    {
        const size_t m0 = (size_t)row0*27;
        for (int i = tid; i < 1728; i += NTHR) scr[i]        = meas[m0 + i];
        for (int i = tid; i < 1728; i += NTHR) scr[1728 + i] = mask[m0 + i];
        const size_t b0 = (size_t)row0*12;
        for (int i = tid; i < 768; i += NTHR)  scr[3456 + i] = baselines[b0 + i];
        if (tid < 384) scr[4224 + tid] = x_prev[(size_t)row0*6 + tid];
        if (tid < 64)  scr[4608 + tid] = dt[row0 + tid];
        // hx -> Hb (bf16 swizzled)
        const size_t hbase = (size_t)row0 * 256;
        #pragma unroll
        for (int ii = 0; ii < 4; ++ii) {
            int cid = tid + ii*NTHR;
            int r  = cid >> 5;
            int k0 = (cid & 31) << 3;
            const float4* p = (const float4*)(hx + hbase + (size_t)r*256 + k0);
            float4 u = p[0], v2 = p[1];
            bf16x8 o;
            o[0]=(short)f2bf(u.x);  o[1]=(short)f2bf(u.y);  o[2]=(short)f2bf(u.z);  o[3]=(short)f2bf(u.w);
            o[4]=(short)f2bf(v2.x); o[5]=(short)f2bf(v2.y); o[6]=(short)f2bf(v2.z); o[7]=(short)f2bf(v2.w);
            *(bf16x8*)(Hb + swzb(r, k0)) = o;
        }
    }
    __syncthreads();   // inputs in LDS; drains vmcnt (prologue slices land too)

    // ====== geometry from LDS scratch -> Rb, xmc ======
    if (w < 4) {
        const int row = lane;
        const float dtv = scr[4608 + row];
        const float dts = dtv * NORM_R;
        float xp[6], xm[6];
        #pragma unroll
        for (int s = 0; s < 6; ++s) xp[s] = scr[4224 + row*6 + s];
        xm[0] = xp[0] + dts*xp[1]; xm[1] = xp[1];
        xm[2] = xp[2] + dts*xp[3]; xm[3] = xp[3];
        xm[4] = xp[4] + dts*xp[5]; xm[5] = xp[5];
        if (w < 3) {
            float xr[6];
            #pragma unroll
            for (int s = 0; s < 6; ++s) {
                float b = (w == 0) ? 0.0f : scr[3456 + row*12 + (w-1)*6 + s];
                xr[s] = xm[s] - b;
            }
            float rxy = sqrtf(xr[0]*xr[0] + xr[2]*xr[2] + 1e-9f);
            float azv = atan2f(xr[2], xr[0]) * (1.0f/PI_F);
            float elv = atan2f(xr[4], rxy)   * (1.0f/PI_F);
            float rrv = sqrtf(xr[0]*xr[0] + xr[2]*xr[2] + xr[4]*xr[4] + 1e-9f);
            float y[9] = {azv, elv, rrv, azv, elv, 0.0f, azv, 0.0f, 0.0f};
            const bool ang[9] = {true,true,false,true,true,false,true,false,false};
            #pragma unroll
            for (int i = 0; i < 9; ++i) {
                int m = w*9 + i;
                float ms = scr[1728 + row*27 + m];
                float v  = scr[row*27 + m] - y[i];
                if (ang[i]) v = v - 2.0f*rintf(v*0.5f);
                v *= ms;
                Rb[row*RSTRIDE + m]      = f2bf(v);
                Rb[row*RSTRIDE + 27 + m] = f2bf(ms);
            }
        } else {
            Rb[row*RSTRIDE + 54] = f2bf(dtv);
            #pragma unroll
            for (int s = 0; s < 6; ++s) Rb[row*RSTRIDE + 55 + s] = f2bf(xm[s]);
            #pragma unroll
            for (int q = 0; q < 12; ++q) Rb[row*RSTRIDE + 61 + q] = f2bf(scr[3456 + row*12 + q]);
            #pragma unroll
            for (int k = 73; k < 96; ++k) Rb[row*RSTRIDE + k] = 0;
            #pragma unroll
            for (int s = 0; s < 6; ++s) xmc[row*6 + s] = xm[s];
        }
    }
    __syncthreads();

    // ====== unified depth-3 slice pipeline ======
    f32x4 ar[2][4], az_[2][4], gi[2][4], gh[2][4];
    #pragma unroll
    for (int i = 0; i < 2; ++i)
        #pragma unroll
        for (int j = 0; j < 4; ++j) {
            ar[i][j]=(f32x4){0,0,0,0}; az_[i][j]=(f32x4){0,0,0,0};
            gi[i][j]=(f32x4){0,0,0,0}; gh[i][j]=(f32x4){0,0,0,0};
        }

    int k = 0;
    // ---- GRU: slices 0..32 (r 0-10, z 11-21, gi 22-24, gh 25-32)
    for (; k < 33; ++k) {
        SLICE_PRE(k);
        const char* sb = STG + ((k & 3) << 14);
        bf16x8 a0, a1;
        if (k < 25) {
            int kb = (k < 11) ? k : (k < 22) ? k-11 : k-22;
            if (kb < 3) { a0 = *(const bf16x8*)(Rb + mrow*RSTRIDE + kb*32 + lk8);
                          a1 = *(const bf16x8*)(Rb + (mrow+16)*RSTRIDE + kb*32 + lk8); }
            else        { a0 = *(const bf16x8*)(Hb + swzb(mrow,    (kb-3)*32 + lk8));
                          a1 = *(const bf16x8*)(Hb + swzb(mrow+16, (kb-3)*32 + lk8)); }
        } else {
            int hk = k - 25;
            a0 = *(const bf16x8*)(Hb + swzb(mrow,    hk*32 + lk8));
            a1 = *(const bf16x8*)(Hb + swzb(mrow+16, hk*32 + lk8));
        }
        __builtin_amdgcn_s_setprio(1);
        if (k < 11) MM8(ar); else if (k < 22) MM8(az_); else if (k < 25) MM8(gi); else MM8(gh);
        __builtin_amdgcn_s_setprio(0);
    }

    // ---- GRU epilogue: h_new -> F1 (bf16)    [slices 33..35 still in flight]
    #pragma unroll
    for (int j = 0; j < 4; ++j) {
        int c = nq*64 + j*16 + lr;
        float brv = b_ih[c] + b_hh[c];
        float bzv = b_ih[256+c] + b_hh[256+c];
        float binv = b_ih[512+c], bhnv = b_hh[512+c];
        #pragma unroll
        for (int i = 0; i < 2; ++i)
            #pragma unroll
            for (int e = 0; e < 4; ++e) {
                int row = mh*32 + i*16 + lk*4 + e;
                float rg = sigm(ar[i][j][e] + brv);
                float zg = sigm(az_[i][j][e] + bzv);
                float ng = tanh_(gi[i][j][e] + binv + rg*(gh[i][j][e] + bhnv));
                float hxv = b2f(*(const ushort*)(Hb + swzb(row, c)));
                float hn = (1.0f - zg)*ng + zg*hxv;
                *(ushort*)(F1 + swzb(row, c)) = f2bf(hn);
            }
    }
    __syncthreads();

    // ---- LayerNorm: F1(h_new) -> Hb(h_ln), + lane-contiguous fp32 h_new store
    {
        const int row = tid >> 3;
        const int o   = tid & 7;
        bf16x8 ch[4];
        float sum = 0.0f, sq = 0.0f;
        #pragma unroll
        for (int c4 = 0; c4 < 4; ++c4) {
            ch[c4] = *(const bf16x8*)(F1 + swzb(row, o*32 + c4*8));
            #pragma unroll
            for (int e = 0; e < 8; ++e) {
                float f = b2f((ushort)ch[c4][e]);
                sum += f; sq += f*f;
            }
        }
        sum += __shfl_xor(sum, 1); sum += __shfl_xor(sum, 2); sum += __shfl_xor(sum, 4);
        sq  += __shfl_xor(sq, 1);  sq  += __shfl_xor(sq, 2);  sq  += __shfl_xor(sq, 4);
        float mu   = sum * (1.0f/256.0f);
        float rstd = rsqrtf(sq*(1.0f/256.0f) - mu*mu + 1e-5f);
        #pragma unroll
        for (int c4 = 0; c4 < 4; ++c4) {
            int col0 = o*32 + c4*8;
            float4 g0 = *(const float4*)(ln_g + col0), g1 = *(const float4*)(ln_g + col0 + 4);
            float4 bb0 = *(const float4*)(ln_b + col0), bb1 = *(const float4*)(ln_b + col0 + 4);
            bf16x8 oo;
            oo[0] = (short)f2bf((b2f((ushort)ch[c4][0]) - mu)*rstd*g0.x + bb0.x);
            oo[1] = (short)f2bf((b2f((ushort)ch[c4][1]) - mu)*rstd*g0.y + bb0.y);
            oo[2] = (short)f2bf((b2f((ushort)ch[c4][2]) - mu)*rstd*g0.z + bb0.z);
            oo[3] = (short)f2bf((b2f((ushort)ch[c4][3]) - mu)*rstd*g0.w + bb0.w);
            oo[4] = (short)f2bf((b2f((ushort)ch[c4][4]) - mu)*rstd*g1.x + bb1.x);
            oo[5] = (short)f2bf((b2f((ushort)ch[c4][5]) - mu)*rstd*g1.y + bb1.y);
            oo[6] = (short)f2bf((b2f((ushort)ch[c4][6]) - mu)*rstd*g1.z + bb1.z);
            oo[7] = (short)f2bf((b2f((ushort)ch[c4][7]) - mu)*rstd*g1.w + bb1.w);
            *(bf16x8*)(Hb + swzb(row, col0)) = oo;
        }
        #pragma unroll
        for (int i = 0; i < 8; ++i) {
            int chunk = i*NTHR + tid;
            int r2 = chunk >> 6;
            int c16 = chunk & 63;
            uint2 d = *(const uint2*)(F1 + swzb(r2, c16*4));
            float4 o4;
            o4.x = b2f((ushort)(d.x & 0xffffu)); o4.y = b2f((ushort)(d.x >> 16));
            o4.z = b2f((ushort)(d.y & 0xffffu)); o4.w = b2f((ushort)(d.y >> 16));
            *(float4*)(hout + (size_t)(row0+r2)*256 + c16*4) = o4;
        }
    }
    __syncthreads();

    // ---- f1 = relu(W1 h_ln + b1): slices 33..40, Hb -> F1
    {
        f32x4 c2[2][4];
        #pragma unroll
        for (int i = 0; i < 2; ++i)
            #pragma unroll
            for (int j = 0; j < 4; ++j) c2[i][j] = (f32x4){0,0,0,0};
        for (; k < 41; ++k) {
            SLICE_PRE(k);
            const char* sb = STG + ((k & 3) << 14);
            int kb = k - 33;
            bf16x8 a0 = *(const bf16x8*)(Hb + swzb(mrow,    kb*32 + lk8));
            bf16x8 a1 = *(const bf16x8*)(Hb + swzb(mrow+16, kb*32 + lk8));
            __builtin_amdgcn_s_setprio(1);
            MM8(c2);
            __builtin_amdgcn_s_setprio(0);
        }
        __syncthreads();   // all Hb reads of the last slice done before F1 overwrite races? (F1 free) — orders f1 stores
        #pragma unroll
        for (int j = 0; j < 4; ++j) {
            int c = nq*64 + j*16 + lr;
            float bv = b1[c];
            #pragma unroll
            for (int i = 0; i < 2; ++i)
                #pragma unroll
                for (int e = 0; e < 4; ++e) {
                    int row = mh*32 + i*16 + lk*4 + e;
                    *(ushort*)(F1 + swzb(row, c)) = f2bf(fmaxf(c2[i][j][e] + bv, 0.0f));
                }
        }
    }
    __syncthreads();

    // ---- f2 = relu(W2 f1 + b2): slices 41..44, F1 -> F2 (overlay Hb)
    ushort* F2 = (ushort*)Hb;   // [64][136] bf16
    {
        f32x4 c3[2][2];
        #pragma unroll
        for (int i = 0; i < 2; ++i)
            #pragma unroll
            for (int j = 0; j < 2; ++j) c3[i][j] = (f32x4){0,0,0,0};
        for (; k < 45; ++k) {
            SLICE_PRE(k);
            const char* sb = STG + ((k & 3) << 14);
            int kb = k - 41;
            __builtin_amdgcn_s_setprio(1);
            #pragma unroll
            for (int ksub = 0; ksub < 2; ++ksub) {
                bf16x8 a0 = *(const bf16x8*)(F1 + swzb(mrow,    kb*64 + ksub*32 + lk8));
                bf16x8 a1 = *(const bf16x8*)(F1 + swzb(mrow+16, kb*64 + ksub*32 + lk8));
                #pragma unroll
                for (int j = 0; j < 2; ++j) {
                    bf16x8 b = rdB16(sb, nq*32 + j*16 + lr, ksub, lk);
                    c3[0][j] = __builtin_amdgcn_mfma_f32_16x16x32_bf16(a0, b, c3[0][j], 0,0,0);
                    c3[1][j] = __builtin_amdgcn_mfma_f32_16x16x32_bf16(a1, b, c3[1][j], 0,0,0);
                }
            }
            __builtin_amdgcn_s_setprio(0);
        }
        __syncthreads();   // h_ln in Hb fully dead before overlay write
        #pragma unroll
        for (int j = 0; j < 2; ++j) {
            int c = nq*32 + j*16 + lr;
            float bv = b2[c];
            #pragma unroll
            for (int i = 0; i < 2; ++i)
                #pragma unroll
                for (int e = 0; e < 4; ++e) {
                    int row = mh*32 + i*16 + lk*4 + e;
                    F2[row*136 + c] = f2bf(fmaxf(c3[i][j][e] + bv, 0.0f));
                }
        }
    }
    __syncthreads();

    // ---- K = clip(W3 f2 + b3): slices 45..48, einsum
    {
        f32x4 c4[2][3];
        #pragma unroll
        for (int i = 0; i < 2; ++i)
            #pragma unroll
            for (int j = 0; j < 3; ++j) c4[i][j] = (f32x4){0,0,0,0};
        const int nfb = nq*3;
        for (; k < N_SLICES; ++k) {
            SLICE_PRE(k);
            const char* sb = STG + ((k & 3) << 14);
            int kb = k - 45;
            bf16x8 a0 = *(const bf16x8*)(F2 + (mrow     )*136 + kb*32 + lk8);
            bf16x8 a1 = *(const bf16x8*)(F2 + (mrow + 16)*136 + kb*32 + lk8);
            __builtin_amdgcn_s_setprio(1);
            #pragma unroll
            for (int j = 0; j < 3; ++j) {
                bf16x8 b = rdA16(sb, (nfb+j)*16 + lr, lk);
                c4[0][j] = __builtin_amdgcn_mfma_f32_16x16x32_bf16(a0, b, c4[0][j], 0,0,0);
                c4[1][j] = __builtin_amdgcn_mfma_f32_16x16x32_bf16(a1, b, c4[1][j], 0,0,0);
            }
            __builtin_amdgcn_s_setprio(0);
        }
        #pragma unroll
        for (int j = 0; j < 3; ++j) {
            int col = (nfb+j)*16 + lr;
            if (col < 162) {
                int s = col / 27, m = col - s*27;
                float bv = b3[col];
                #pragma unroll
                for (int i = 0; i < 2; ++i)
                    #pragma unroll
                    for (int e = 0; e < 4; ++e) {
                        int row = mh*32 + i*16 + lk*4 + e;
                        float K  = fminf(fmaxf(c4[i][j][e] + bv, -3.0f), 3.0f);
                        float iv = b2f(Rb[row*RSTRIDE + m]);
                        atomicAdd(&xmc[row*6 + s], K*iv);
                    }
            }
        }
    }
    __syncthreads();

    for (int t = tid; t < ROWS*6; t += NTHR) {
        int row = t / 6, s = t - row*6;
        float v = fminf(fmaxf(xmc[t], -5.0f), 5.0f);
        out[(size_t)(row0+row)*6 + s] = v;
    }
}

extern "C" void kernel_launch(void* const* d_in, const int* in_sizes, int n_in,
                              void* d_out, int out_size, void* d_ws, size_t ws_size,
                              hipStream_t stream) {
    const float* meas      = (const float*)d_in[0];
    const float* mask      = (const float*)d_in[1];
    const float* dtv       = (const float*)d_in[2];
    const float* baselines = (const float*)d_in[3];
    const float* x_prev    = (const float*)d_in[4];
    const float* hx        = (const float*)d_in[5];
    const float* W_ih      = (const float*)d_in[6];
    const float* W_hh      = (const float*)d_in[7];
    const float* b_ih      = (const float*)d_in[8];
    const float* b_hh      = (const float*)d_in[9];
    const float* ln_g      = (const float*)d_in[10];
    const float* ln_b      = (const float*)d_in[11];
    const float* W1        = (const float*)d_in[12];
    const float* b1        = (const float*)d_in[13];
    const float* W2        = (const float*)d_in[14];
    const float* b2        = (const float*)d_in[15];
    const float* W3        = (const float*)d_in[16];
    const float* b3        = (const float*)d_in[17];
    ushort* wsb = (ushort*)d_ws;
    float* outp = (float*)d_out;

    prep_weights<<<(W_TOTAL + 255)/256, 256, 0, stream>>>(W_ih, W_hh, W1, W2, W3, wsb);
    knet_mfma<<<NWG, NTHR, LDS_TOTAL, stream>>>(
        meas, mask, dtv, baselines, x_prev, hx,
        b_ih, b_hh, ln_g, ln_b, b1, b2, b3, wsb, outp);
}

// Round 6
// 851.364 us; speedup vs baseline: 1.2964x; 1.2964x over previous
//
#include <hip/hip_runtime.h>
#include <math.h>

#define B_TOTAL  262144
#define ROWS     64
#define NWG      (B_TOTAL/ROWS)   // 4096
#define NTHR     512
#define PI_F     3.14159265358979323846f
#define NORM_R   (500.0f/150000.0f)

typedef float  f32x4  __attribute__((ext_vector_type(4)));
typedef short  bf16x8 __attribute__((ext_vector_type(8)));

// ---- bf16 weight workspace layout (ushort units) ----
#define SRZ 352   // [512][352]: k<73 = W_ih rows 0..511 ; k 96..351 = W_hh rows 0..511
#define SNI 96    // [256][96]:  W_ih rows 512..767 (n-gate input), k>=73 zero
#define SNH 256   // [256][256]: W_hh rows 512..767
#define SW1 256
#define SW2 256
#define SW3 128   // [256][128]: rows >=162 zero
#define OFF_RZ 0
#define OFF_NI (OFF_RZ + 512*SRZ)
#define OFF_NH (OFF_NI + 256*SNI)
#define OFF_W1 (OFF_NH + 256*SNH)
#define OFF_W2 (OFF_W1 + 256*SW1)
#define OFF_W3 (OFF_W2 + 128*SW2)
#define W_TOTAL (OFF_W3 + 256*SW3)  // 401408 ushort = 784 KiB

// ---- LDS layout (byte offsets), ROWS=64 ----
#define RSTRIDE 104
#define LDS_HB   (ROWS*RSTRIDE*2)          // Rb: [64][104] bf16           13312
#define LDS_F1   (LDS_HB + ROWS*256*2)     // Hb: [64][256] bf16 swizzled  32768
#define LDS_STG  (LDS_F1 + ROWS*256*2)     // F1: [64][256] bf16 swizzled  32768 (also input scratch)
#define LDS_XMC  (LDS_STG + 4*16384)       // STG: 4 x 16KB quad-buffer
#define LDS_TOTAL (LDS_XMC + ROWS*6*4)     // xmc: [64][6] f32  => 145920 B (1 WG/CU)

#define WAIT_VM4 asm volatile("s_waitcnt vmcnt(4)" ::: "memory")
#define WAIT_VM2 asm volatile("s_waitcnt vmcnt(2)" ::: "memory")
#define WAIT_VM0 asm volatile("s_waitcnt vmcnt(0)" ::: "memory")
#define BARv     __builtin_amdgcn_s_barrier()
// global-slice tail-aware wait+barrier (depth-3, 2 loads/stage)
#define PRE_G(g) do { if ((g) < 47) WAIT_VM4; else if ((g) == 47) WAIT_VM2; else WAIT_VM0; BARv; } while(0)

__device__ __forceinline__ ushort f2bf(float f){
    union { float f; unsigned u; } v; v.f = f;
    unsigned r = v.u + 0x7FFFu + ((v.u >> 16) & 1u);
    return (ushort)(r >> 16);
}
__device__ __forceinline__ float b2f(ushort u){
    union { unsigned u; float f; } v; v.u = ((unsigned)u) << 16;
    return v.f;
}
__device__ __forceinline__ float sigm(float x){ return 1.0f/(1.0f+__expf(-x)); }
__device__ __forceinline__ float tanh_(float x){ return 1.0f - 2.0f/(__expf(2.0f*x)+1.0f); }
__device__ __forceinline__ int swzb(int row, int k){          // [*][256] bf16, 16B-XOR swizzle
    return ((row<<9) + (k<<1)) ^ ((row&7)<<4);
}

// stage a 16KB slice: 256 cols x 64B (32 k-elems), XOR-swizzled k-chunks.
__device__ __forceinline__ void stageA(const ushort* pb, int stride, int koff,
                                       char* dst, int w, int lane) {
    #pragma unroll
    for (int i = 0; i < 2; ++i) {
        int idx  = (w*2 + i)*64 + lane;        // 0..1023
        int col  = idx >> 2;
        int kq   = (idx & 3) ^ ((col >> 1) & 3);
        const ushort* g = pb + (size_t)col*stride + koff + kq*8;
        __builtin_amdgcn_global_load_lds(
            (const __attribute__((address_space(1))) void*)g,
            (__attribute__((address_space(3))) void*)(dst + (w*2+i)*1024),
            16, 0, 0);
    }
}
// stage a 16KB slice: 128 cols x 128B (64 k-elems)
__device__ __forceinline__ void stageB(const ushort* pb, int stride, int koff,
                                       char* dst, int w, int lane) {
    #pragma unroll
    for (int i = 0; i < 2; ++i) {
        int idx  = (w*2 + i)*64 + lane;
        int col  = idx >> 3;
        int kq   = (idx & 7) ^ (col & 7);
        const ushort* g = pb + (size_t)col*stride + koff + kq*8;
        __builtin_amdgcn_global_load_lds(
            (const __attribute__((address_space(1))) void*)g,
            (__attribute__((address_space(3))) void*)(dst + (w*2+i)*1024),
            16, 0, 0);
    }
}
__device__ __forceinline__ bf16x8 rdA16(const char* sb, int col, int lk){
    int slot = lk ^ ((col >> 1) & 3);
    return *(const bf16x8*)(sb + col*64 + slot*16);
}
__device__ __forceinline__ bf16x8 rdB16(const char* sb, int col, int ksub, int lk){
    int slot = ((ksub<<2)|lk) ^ (col & 7);
    return *(const bf16x8*)(sb + col*128 + slot*16);
}

__global__ void prep_weights(const float* __restrict__ W_ih, const float* __restrict__ W_hh,
                             const float* __restrict__ W1, const float* __restrict__ W2,
                             const float* __restrict__ W3, ushort* __restrict__ ws)
{
    int id = blockIdx.x*256 + threadIdx.x;
    if (id >= W_TOTAL) return;
    float v = 0.0f;
    if (id < OFF_NI) {
        int t = id; int n = t / SRZ, k = t - n*SRZ;
        if (k < 73) v = W_ih[n*73 + k];
        else if (k >= 96) v = W_hh[n*256 + (k-96)];
    } else if (id < OFF_NH) {
        int t = id - OFF_NI; int n = t / SNI, k = t - n*SNI;
        if (k < 73) v = W_ih[(512+n)*73 + k];
    } else if (id < OFF_W1) {
        int t = id - OFF_NH; int n = t >> 8, k = t & 255;
        v = W_hh[(512+n)*256 + k];
    } else if (id < OFF_W2) {
        int t = id - OFF_W1; int n = t >> 8, k = t & 255;
        v = W1[n*256 + k];
    } else if (id < OFF_W3) {
        int t = id - OFF_W2; int n = t >> 8, k = t & 255;
        v = W2[n*256 + k];
    } else {
        int t = id - OFF_W3; int n = t >> 7, k = t & 127;
        if (n < 162) v = W3[n*128 + k];
    }
    ws[id] = f2bf(v);
}

#define MM8(ACC) do { _Pragma("unroll") \
    for (int j = 0; j < 4; ++j) { \
        bf16x8 b = rdA16(sb, nq*64 + j*16 + lr, lk); \
        ACC[0][j] = __builtin_amdgcn_mfma_f32_16x16x32_bf16(a0, b, ACC[0][j], 0,0,0); \
        ACC[1][j] = __builtin_amdgcn_mfma_f32_16x16x32_bf16(a1, b, ACC[1][j], 0,0,0); \
    } } while(0)

__global__ __launch_bounds__(NTHR, 1) void knet_mfma(
    const float* __restrict__ meas, const float* __restrict__ mask,
    const float* __restrict__ dt,   const float* __restrict__ baselines,
    const float* __restrict__ x_prev, const float* __restrict__ hx,
    const float* __restrict__ b_ih, const float* __restrict__ b_hh,
    const float* __restrict__ ln_g, const float* __restrict__ ln_b,
    const float* __restrict__ b1,   const float* __restrict__ b2,
    const float* __restrict__ b3,
    const ushort* __restrict__ ws,
    float* __restrict__ out)
{
    extern __shared__ char smem[];
    ushort* Rb  = (ushort*)smem;
    char*   Hb  = smem + LDS_HB;
    char*   F1  = smem + LDS_F1;
    char*   STG = smem + LDS_STG;
    float*  xmc = (float*)(smem + LDS_XMC);

    const int tid  = threadIdx.x;
    const int w    = __builtin_amdgcn_readfirstlane(tid >> 6);
    const int nq   = w & 3;
    const int mh   = w >> 2;
    const int lane = tid & 63;
    const int lr   = lane & 15;
    const int lk   = lane >> 4;
    const int lk8  = lk * 8;
    const int row0 = blockIdx.x * ROWS;
    const int mrow = mh*32 + lr;
    float* hout = out + (size_t)B_TOTAL*6;

    // prologue: slices 0,1,2 in flight (resident after first __syncthreads drain)
    stageA(ws + OFF_RZ, SRZ, 0*32, STG + (0<<14), w, lane);
    stageA(ws + OFF_RZ, SRZ, 1*32, STG + (1<<14), w, lane);
    stageA(ws + OFF_RZ, SRZ, 2*32, STG + (2<<14), w, lane);

    // ====== coalesced input staging -> F1 scratch (f32) ======
    float* scr = (float*)F1;
    {
        const size_t m0 = (size_t)row0*27;
        for (int i = tid; i < 1728; i += NTHR) scr[i]        = meas[m0 + i];
        for (int i = tid; i < 1728; i += NTHR) scr[1728 + i] = mask[m0 + i];
        const size_t b0 = (size_t)row0*12;
        for (int i = tid; i < 768; i += NTHR)  scr[3456 + i] = baselines[b0 + i];
        if (tid < 384) scr[4224 + tid] = x_prev[(size_t)row0*6 + tid];
        if (tid < 64)  scr[4608 + tid] = dt[row0 + tid];
        const size_t hbase = (size_t)row0 * 256;
        #pragma unroll
        for (int ii = 0; ii < 4; ++ii) {
            int cid = tid + ii*NTHR;
            int r  = cid >> 5;
            int k0 = (cid & 31) << 3;
            const float4* p = (const float4*)(hx + hbase + (size_t)r*256 + k0);
            float4 u = p[0], v2 = p[1];
            bf16x8 o;
            o[0]=(short)f2bf(u.x);  o[1]=(short)f2bf(u.y);  o[2]=(short)f2bf(u.z);  o[3]=(short)f2bf(u.w);
            o[4]=(short)f2bf(v2.x); o[5]=(short)f2bf(v2.y); o[6]=(short)f2bf(v2.z); o[7]=(short)f2bf(v2.w);
            *(bf16x8*)(Hb + swzb(r, k0)) = o;
        }
    }
    __syncthreads();

    // ====== geometry from LDS scratch -> Rb, xmc ======
    if (w < 4) {
        const int row = lane;
        const float dtv = scr[4608 + row];
        const float dts = dtv * NORM_R;
        float xp[6], xm[6];
        #pragma unroll
        for (int s = 0; s < 6; ++s) xp[s] = scr[4224 + row*6 + s];
        xm[0] = xp[0] + dts*xp[1]; xm[1] = xp[1];
        xm[2] = xp[2] + dts*xp[3]; xm[3] = xp[3];
        xm[4] = xp[4] + dts*xp[5]; xm[5] = xp[5];
        if (w < 3) {
            float xr[6];
            #pragma unroll
            for (int s = 0; s < 6; ++s) {
                float b = (w == 0) ? 0.0f : scr[3456 + row*12 + (w-1)*6 + s];
                xr[s] = xm[s] - b;
            }
            float rxy = sqrtf(xr[0]*xr[0] + xr[2]*xr[2] + 1e-9f);
            float azv = atan2f(xr[2], xr[0]) * (1.0f/PI_F);
            float elv = atan2f(xr[4], rxy)   * (1.0f/PI_F);
            float rrv = sqrtf(xr[0]*xr[0] + xr[2]*xr[2] + xr[4]*xr[4] + 1e-9f);
            float y[9] = {azv, elv, rrv, azv, elv, 0.0f, azv, 0.0f, 0.0f};
            const bool ang[9] = {true,true,false,true,true,false,true,false,false};
            #pragma unroll
            for (int i = 0; i < 9; ++i) {
                int m = w*9 + i;
                float ms = scr[1728 + row*27 + m];
                float v  = scr[row*27 + m] - y[i];
                if (ang[i]) v = v - 2.0f*rintf(v*0.5f);
                v *= ms;
                Rb[row*RSTRIDE + m]      = f2bf(v);
                Rb[row*RSTRIDE + 27 + m] = f2bf(ms);
            }
        } else {
            Rb[row*RSTRIDE + 54] = f2bf(dtv);
            #pragma unroll
            for (int s = 0; s < 6; ++s) Rb[row*RSTRIDE + 55 + s] = f2bf(xm[s]);
            #pragma unroll
            for (int q = 0; q < 12; ++q) Rb[row*RSTRIDE + 61 + q] = f2bf(scr[3456 + row*12 + q]);
            #pragma unroll
            for (int k = 73; k < 96; ++k) Rb[row*RSTRIDE + k] = 0;
            #pragma unroll
            for (int s = 0; s < 6; ++s) xmc[row*6 + s] = xm[s];
        }
    }
    __syncthreads();

    // ====== GRU: contiguous 33-slice depth-3 pipeline (specialized loops) ======
    f32x4 ar[2][4], az_[2][4], gi_[2][4], gh_[2][4];
    #pragma unroll
    for (int i = 0; i < 2; ++i)
        #pragma unroll
        for (int j = 0; j < 4; ++j) {
            ar[i][j]=(f32x4){0,0,0,0}; az_[i][j]=(f32x4){0,0,0,0};
            gi_[i][j]=(f32x4){0,0,0,0}; gh_[i][j]=(f32x4){0,0,0,0};
        }

    // ---- r: slices 0..10
    #pragma unroll
    for (int kb = 0; kb < 11; ++kb) {
        PRE_G(kb);
        char* dst = STG + (((kb+3)&3)<<14);
        if (kb < 8) stageA(ws + OFF_RZ, SRZ, (kb+3)*32, dst, w, lane);
        else        stageA(ws + OFF_RZ + (size_t)256*SRZ, SRZ, (kb-8)*32, dst, w, lane);
        const char* sb = STG + ((kb&3)<<14);
        bf16x8 a0, a1;
        if (kb < 3) { a0 = *(const bf16x8*)(Rb + mrow*RSTRIDE + kb*32 + lk8);
                      a1 = *(const bf16x8*)(Rb + (mrow+16)*RSTRIDE + kb*32 + lk8); }
        else        { a0 = *(const bf16x8*)(Hb + swzb(mrow,    (kb-3)*32 + lk8));
                      a1 = *(const bf16x8*)(Hb + swzb(mrow+16, (kb-3)*32 + lk8)); }
        __builtin_amdgcn_s_setprio(1);
        MM8(ar);
        __builtin_amdgcn_s_setprio(0);
    }
    // ---- z: slices 11..21
    #pragma unroll
    for (int kb = 0; kb < 11; ++kb) {
        PRE_G(11+kb);
        char* dst = STG + (((kb+14)&3)<<14);
        if (kb < 8) stageA(ws + OFF_RZ + (size_t)256*SRZ, SRZ, (kb+3)*32, dst, w, lane);
        else        stageA(ws + OFF_NI, SNI, (kb-8)*32, dst, w, lane);
        const char* sb = STG + (((11+kb)&3)<<14);
        bf16x8 a0, a1;
        if (kb < 3) { a0 = *(const bf16x8*)(Rb + mrow*RSTRIDE + kb*32 + lk8);
                      a1 = *(const bf16x8*)(Rb + (mrow+16)*RSTRIDE + kb*32 + lk8); }
        else        { a0 = *(const bf16x8*)(Hb + swzb(mrow,    (kb-3)*32 + lk8));
                      a1 = *(const bf16x8*)(Hb + swzb(mrow+16, (kb-3)*32 + lk8)); }
        __builtin_amdgcn_s_setprio(1);
        MM8(az_);
        __builtin_amdgcn_s_setprio(0);
    }
    // ---- gi: slices 22..24
    #pragma unroll
    for (int kb = 0; kb < 3; ++kb) {
        PRE_G(22+kb);
        char* dst = STG + (((kb+25)&3)<<14);
        stageA(ws + OFF_NH, SNH, kb*32, dst, w, lane);          // slices 25,26,27
        const char* sb = STG + (((22+kb)&3)<<14);
        bf16x8 a0 = *(const bf16x8*)(Rb + mrow*RSTRIDE + kb*32 + lk8);
        bf16x8 a1 = *(const bf16x8*)(Rb + (mrow+16)*RSTRIDE + kb*32 + lk8);
        __builtin_amdgcn_s_setprio(1);
        MM8(gi_);
        __builtin_amdgcn_s_setprio(0);
    }
    // ---- gh: slices 25..32
    #pragma unroll
    for (int kb = 0; kb < 8; ++kb) {
        PRE_G(25+kb);
        char* dst = STG + (((kb+28)&3)<<14);
        if (kb < 5) stageA(ws + OFF_NH, SNH, (kb+3)*32, dst, w, lane);   // 28..32
        else        stageA(ws + OFF_W1, SW1, (kb-5)*32, dst, w, lane);   // 33,34,35
        const char* sb = STG + (((25+kb)&3)<<14);
        bf16x8 a0 = *(const bf16x8*)(Hb + swzb(mrow,    kb*32 + lk8));
        bf16x8 a1 = *(const bf16x8*)(Hb + swzb(mrow+16, kb*32 + lk8));
        __builtin_amdgcn_s_setprio(1);
        MM8(gh_);
        __builtin_amdgcn_s_setprio(0);
    }
    // ---- GRU epilogue: h_new -> F1 (bf16)  [slices 33..35 in flight]
    #pragma unroll
    for (int j = 0; j < 4; ++j) {
        int c = nq*64 + j*16 + lr;
        float brv = b_ih[c] + b_hh[c];
        float bzv = b_ih[256+c] + b_hh[256+c];
        float binv = b_ih[512+c], bhnv = b_hh[512+c];
        #pragma unroll
        for (int i = 0; i < 2; ++i)
            #pragma unroll
            for (int e = 0; e < 4; ++e) {
                int row = mh*32 + i*16 + lk*4 + e;
                float rg = sigm(ar[i][j][e] + brv);
                float zg = sigm(az_[i][j][e] + bzv);
                float ng = tanh_(gi_[i][j][e] + binv + rg*(gh_[i][j][e] + bhnv));
                float hxv = b2f(*(const ushort*)(Hb + swzb(row, c)));
                float hn = (1.0f - zg)*ng + zg*hxv;
                *(ushort*)(F1 + swzb(row, c)) = f2bf(hn);
            }
    }
    __syncthreads();   // drains slices 33..35 -> resident

    // ---- LayerNorm: F1(h_new) -> Hb(h_ln), + lane-contiguous fp32 h_new store
    {
        const int row = tid >> 3;
        const int o   = tid & 7;
        bf16x8 ch[4];
        float sum = 0.0f, sq = 0.0f;
        #pragma unroll
        for (int c4 = 0; c4 < 4; ++c4) {
            ch[c4] = *(const bf16x8*)(F1 + swzb(row, o*32 + c4*8));
            #pragma unroll
            for (int e = 0; e < 8; ++e) {
                float f = b2f((ushort)ch[c4][e]);
                sum += f; sq += f*f;
            }
        }
        sum += __shfl_xor(sum, 1); sum += __shfl_xor(sum, 2); sum += __shfl_xor(sum, 4);
        sq  += __shfl_xor(sq, 1);  sq  += __shfl_xor(sq, 2);  sq  += __shfl_xor(sq, 4);
        float mu   = sum * (1.0f/256.0f);
        float rstd = rsqrtf(sq*(1.0f/256.0f) - mu*mu + 1e-5f);
        #pragma unroll
        for (int c4 = 0; c4 < 4; ++c4) {
            int col0 = o*32 + c4*8;
            float4 g0 = *(const float4*)(ln_g + col0), g1 = *(const float4*)(ln_g + col0 + 4);
            float4 bb0 = *(const float4*)(ln_b + col0), bb1 = *(const float4*)(ln_b + col0 + 4);
            bf16x8 oo;
            oo[0] = (short)f2bf((b2f((ushort)ch[c4][0]) - mu)*rstd*g0.x + bb0.x);
            oo[1] = (short)f2bf((b2f((ushort)ch[c4][1]) - mu)*rstd*g0.y + bb0.y);
            oo[2] = (short)f2bf((b2f((ushort)ch[c4][2]) - mu)*rstd*g0.z + bb0.z);
            oo[3] = (short)f2bf((b2f((ushort)ch[c4][3]) - mu)*rstd*g0.w + bb0.w);
            oo[4] = (short)f2bf((b2f((ushort)ch[c4][4]) - mu)*rstd*g1.x + bb1.x);
            oo[5] = (short)f2bf((b2f((ushort)ch[c4][5]) - mu)*rstd*g1.y + bb1.y);
            oo[6] = (short)f2bf((b2f((ushort)ch[c4][6]) - mu)*rstd*g1.z + bb1.z);
            oo[7] = (short)f2bf((b2f((ushort)ch[c4][7]) - mu)*rstd*g1.w + bb1.w);
            *(bf16x8*)(Hb + swzb(row, col0)) = oo;
        }
        #pragma unroll
        for (int i = 0; i < 8; ++i) {
            int chunk = i*NTHR + tid;
            int r2 = chunk >> 6;
            int c16 = chunk & 63;
            uint2 d = *(const uint2*)(F1 + swzb(r2, c16*4));
            float4 o4;
            o4.x = b2f((ushort)(d.x & 0xffffu)); o4.y = b2f((ushort)(d.x >> 16));
            o4.z = b2f((ushort)(d.y & 0xffffu)); o4.w = b2f((ushort)(d.y >> 16));
            *(float4*)(hout + (size_t)(row0+r2)*256 + c16*4) = o4;
        }
    }
    __syncthreads();

    // ---- f1 = relu(W1 h_ln + b1): slices 33..40, Hb -> F1
    {
        f32x4 c2[2][4];
        #pragma unroll
        for (int i = 0; i < 2; ++i)
            #pragma unroll
            for (int j = 0; j < 4; ++j) c2[i][j] = (f32x4){0,0,0,0};
        #pragma unroll
        for (int kb = 0; kb < 8; ++kb) {
            PRE_G(33+kb);
            char* dst = STG + (((kb+36)&3)<<14);
            if (kb < 5) stageA(ws + OFF_W1, SW1, (kb+3)*32, dst, w, lane);   // 36..40
            else        stageB(ws + OFF_W2, SW2, (kb-5)*64, dst, w, lane);   // 41,42,43
            const char* sb = STG + (((33+kb)&3)<<14);
            bf16x8 a0 = *(const bf16x8*)(Hb + swzb(mrow,    kb*32 + lk8));
            bf16x8 a1 = *(const bf16x8*)(Hb + swzb(mrow+16, kb*32 + lk8));
            __builtin_amdgcn_s_setprio(1);
            MM8(c2);
            __builtin_amdgcn_s_setprio(0);
        }
        #pragma unroll
        for (int j = 0; j < 4; ++j) {
            int c = nq*64 + j*16 + lr;
            float bv = b1[c];
            #pragma unroll
            for (int i = 0; i < 2; ++i)
                #pragma unroll
                for (int e = 0; e < 4; ++e) {
                    int row = mh*32 + i*16 + lk*4 + e;
                    *(ushort*)(F1 + swzb(row, c)) = f2bf(fmaxf(c2[i][j][e] + bv, 0.0f));
                }
        }
    }
    __syncthreads();

    // ---- f2 = relu(W2 f1 + b2): slices 41..44, F1 -> F2 (overlay Hb)
    ushort* F2 = (ushort*)Hb;   // [64][136] bf16
    {
        f32x4 c3[2][2];
        #pragma unroll
        for (int i = 0; i < 2; ++i)
            #pragma unroll
            for (int j = 0; j < 2; ++j) c3[i][j] = (f32x4){0,0,0,0};
        #pragma unroll
        for (int kb = 0; kb < 4; ++kb) {
            PRE_G(41+kb);
            char* dst = STG + (((kb+44)&3)<<14);
            if (kb < 1) stageB(ws + OFF_W2, SW2, (kb+3)*64, dst, w, lane);   // 44
            else        stageA(ws + OFF_W3, SW3, (kb-1)*32, dst, w, lane);   // 45,46,47
            const char* sb = STG + (((41+kb)&3)<<14);
            __builtin_amdgcn_s_setprio(1);
            #pragma unroll
            for (int ksub = 0; ksub < 2; ++ksub) {
                bf16x8 a0 = *(const bf16x8*)(F1 + swzb(mrow,    kb*64 + ksub*32 + lk8));
                bf16x8 a1 = *(const bf16x8*)(F1 + swzb(mrow+16, kb*64 + ksub*32 + lk8));
                #pragma unroll
                for (int j = 0; j < 2; ++j) {
                    bf16x8 b = rdB16(sb, nq*32 + j*16 + lr, ksub, lk);
                    c3[0][j] = __builtin_amdgcn_mfma_f32_16x16x32_bf16(a0, b, c3[0][j], 0,0,0);
                    c3[1][j] = __builtin_amdgcn_mfma_f32_16x16x32_bf16(a1, b, c3[1][j], 0,0,0);
                }
            }
            __builtin_amdgcn_s_setprio(0);
        }
        __syncthreads();   // all F1 reads + Hb fully dead before overlay write
        #pragma unroll
        for (int j = 0; j < 2; ++j) {
            int c = nq*32 + j*16 + lr;
            float bv = b2[c];
            #pragma unroll
            for (int i = 0; i < 2; ++i)
                #pragma unroll
                for (int e = 0; e < 4; ++e) {
                    int row = mh*32 + i*16 + lk*4 + e;
                    F2[row*136 + c] = f2bf(fmaxf(c3[i][j][e] + bv, 0.0f));
                }
        }
    }
    __syncthreads();

    // ---- K = clip(W3 f2 + b3): slices 45..48, einsum
    {
        f32x4 c4[2][3];
        #pragma unroll
        for (int i = 0; i < 2; ++i)
            #pragma unroll
            for (int j = 0; j < 3; ++j) c4[i][j] = (f32x4){0,0,0,0};
        const int nfb = nq*3;
        #pragma unroll
        for (int kb = 0; kb < 4; ++kb) {
            PRE_G(45+kb);
            if (kb < 1) stageA(ws + OFF_W3, SW3, (kb+3)*32, STG + (((kb+48)&3)<<14), w, lane);  // 48
            const char* sb = STG + (((45+kb)&3)<<14);
            bf16x8 a0 = *(const bf16x8*)(F2 + (mrow     )*136 + kb*32 + lk8);
            bf16x8 a1 = *(const bf16x8*)(F2 + (mrow + 16)*136 + kb*32 + lk8);
            __builtin_amdgcn_s_setprio(1);
            #pragma unroll
            for (int j = 0; j < 3; ++j) {
                bf16x8 b = rdA16(sb, (nfb+j)*16 + lr, lk);
                c4[0][j] = __builtin_amdgcn_mfma_f32_16x16x32_bf16(a0, b, c4[0][j], 0,0,0);
                c4[1][j] = __builtin_amdgcn_mfma_f32_16x16x32_bf16(a1, b, c4[1][j], 0,0,0);
            }
            __builtin_amdgcn_s_setprio(0);
        }
        #pragma unroll
        for (int j = 0; j < 3; ++j) {
            int col = (nfb+j)*16 + lr;
            if (col < 162) {
                int s = col / 27, m = col - s*27;
                float bv = b3[col];
                #pragma unroll
                for (int i = 0; i < 2; ++i)
                    #pragma unroll
                    for (int e = 0; e < 4; ++e) {
                        int row = mh*32 + i*16 + lk*4 + e;
                        float K  = fminf(fmaxf(c4[i][j][e] + bv, -3.0f), 3.0f);
                        float iv = b2f(Rb[row*RSTRIDE + m]);
                        atomicAdd(&xmc[row*6 + s], K*iv);
                    }
            }
        }
    }
    __syncthreads();

    for (int t = tid; t < ROWS*6; t += NTHR) {
        int row = t / 6, s = t - row*6;
        float v = fminf(fmaxf(xmc[t], -5.0f), 5.0f);
        out[(size_t)(row0+row)*6 + s] = v;
    }
}

extern "C" void kernel_launch(void* const* d_in, const int* in_sizes, int n_in,
                              void* d_out, int out_size, void* d_ws, size_t ws_size,
                              hipStream_t stream) {
    const float* meas      = (const float*)d_in[0];
    const float* mask      = (const float*)d_in[1];
    const float* dtv       = (const float*)d_in[2];
    const float* baselines = (const float*)d_in[3];
    const float* x_prev    = (const float*)d_in[4];
    const float* hx        = (const float*)d_in[5];
    const float* W_ih      = (const float*)d_in[6];
    const float* W_hh      = (const float*)d_in[7];
    const float* b_ih      = (const float*)d_in[8];
    const float* b_hh      = (const float*)d_in[9];
    const float* ln_g      = (const float*)d_in[10];
    const float* ln_b      = (const float*)d_in[11];
    const float* W1        = (const float*)d_in[12];
    const float* b1        = (const float*)d_in[13];
    const float* W2        = (const float*)d_in[14];
    const float* b2        = (const float*)d_in[15];
    const float* W3        = (const float*)d_in[16];
    const float* b3        = (const float*)d_in[17];
    ushort* wsb = (ushort*)d_ws;
    float* outp = (float*)d_out;

    prep_weights<<<(W_TOTAL + 255)/256, 256, 0, stream>>>(W_ih, W_hh, W1, W2, W3, wsb);
    knet_mfma<<<NWG, NTHR, LDS_TOTAL, stream>>>(
        meas, mask, dtv, baselines, x_prev, hx,
        b_ih, b_hh, ln_g, ln_b, b1, b2, b3, wsb, outp);
}

// Round 7
// 696.127 us; speedup vs baseline: 1.5855x; 1.2230x over previous
//
#include <hip/hip_runtime.h>
#include <math.h>

#define B_TOTAL  262144
#define ROWS     64
#define NWG      (B_TOTAL/ROWS)   // 4096
#define NTHR     512
#define PI_F     3.14159265358979323846f
#define NORM_R   (500.0f/150000.0f)

typedef float  f32x4  __attribute__((ext_vector_type(4)));
typedef short  bf16x8 __attribute__((ext_vector_type(8)));

// ---- ws layout (ushorts): pre-swizzled LDS images ----
#define GRU_SLAB 24576                 // 48KB: [r|z|n] x (256 cols x 64B) at one kb
#define OFF_GRU  0                     // 11 slabs (kb 0..10)
#define OFF_W1   (11*GRU_SLAB)         // 270336: 8 kb x 8192 (16KB each)
#define OFF_W2   (OFF_W1 + 8*8192)     // 335872: 8 kb x 4096 (8KB each, 128 cols)
#define OFF_W3   (OFF_W2 + 8*4096)     // 368640: 4 kb x 8192 (16KB, cols>=162 zero)
#define W_TOTAL  (OFF_W3 + 4*8192)     // 401408 ushorts = 784KB

// ---- LDS layout (bytes) ----
#define LDS_RBF2  0                    // Rb [64][104]u16 (13.3KB) -> F2 [64][136]u16 (17KB)
#define LDS_HB    17408                // Hb [64][256] bf16 swizzled: hx -> h_ln -> f1acts
#define LDS_STG   (LDS_HB + 32768)     // 50176: 2 x 48KB slab dbuf (buf1 also input scratch)
#define LDS_XMC   (LDS_STG + 2*49152)  // 148480: [64][6] f32
#define LDS_LNS   (LDS_XMC + 1536)     // 150016: LN partials [64][4][2] f32
#define LDS_TOTAL (LDS_LNS + 2048)     // 152064

#define WAIT_VM0 asm volatile("s_waitcnt vmcnt(0)" ::: "memory")
#define BARv     __builtin_amdgcn_s_barrier()

__device__ __forceinline__ ushort f2bf(float f){
    union { float f; unsigned u; } v; v.f = f;
    unsigned r = v.u + 0x7FFFu + ((v.u >> 16) & 1u);
    return (ushort)(r >> 16);
}
__device__ __forceinline__ float b2f(ushort u){
    union { unsigned u; float f; } v; v.u = ((unsigned)u) << 16;
    return v.f;
}
__device__ __forceinline__ float sigm(float x){ return 1.0f/(1.0f+__expf(-x)); }
__device__ __forceinline__ float tanh_(float x){ return 1.0f - 2.0f/(__expf(2.0f*x)+1.0f); }
__device__ __forceinline__ int swzb(int row, int k){          // Hb [64][256] bf16 16B-XOR
    return ((row<<9) + (k<<1)) ^ ((row&7)<<4);
}
// weight-frag read from slab: W[col][k-chunk lk], slot-XOR for bank spread
__device__ __forceinline__ bf16x8 rdW(const char* gb, int col, int lk){
    int slot = lk ^ ((col >> 1) & 3);
    return *(const bf16x8*)(gb + col*64 + slot*16);
}
// fully-linear slab staging: ws image -> LDS, contiguous on both sides
template<int N>
__device__ __forceinline__ void stage_lin(const ushort* src, char* dst, int w, int lane){
    #pragma unroll
    for (int i = 0; i < N; ++i) {
        __builtin_amdgcn_global_load_lds(
            (const __attribute__((address_space(1))) void*)(src + (size_t)(i*512 + w*64 + lane)*8),
            (__attribute__((address_space(3))) void*)(dst + i*8192 + w*1024),
            16, 0, 0);
    }
}
// one gate/layer fragment cluster: 4 col-frags x 2 row-frags (operand-swapped MFMA)
__device__ __forceinline__ void mm4(const char* gb, int colbase, int lr, int lk,
                                    bf16x8 a0, bf16x8 a1, f32x4 acc[2][4]){
    #pragma unroll
    for (int j = 0; j < 4; ++j) {
        bf16x8 wf = rdW(gb, colbase + j*16 + lr, lk);
        acc[0][j] = __builtin_amdgcn_mfma_f32_16x16x32_bf16(wf, a0, acc[0][j], 0,0,0);
        acc[1][j] = __builtin_amdgcn_mfma_f32_16x16x32_bf16(wf, a1, acc[1][j], 0,0,0);
    }
}

__global__ void prep_weights(const float* __restrict__ W_ih, const float* __restrict__ W_hh,
                             const float* __restrict__ W1, const float* __restrict__ W2,
                             const float* __restrict__ W3, ushort* __restrict__ ws)
{
    int id = blockIdx.x*256 + threadIdx.x;
    if (id >= W_TOTAL) return;
    float v = 0.0f;
    if (id < OFF_W1) {                       // GRU slabs: [gate][col][slot][e]
        int slab = id / GRU_SLAB, u = id % GRU_SLAB;
        int gate = u >> 13, u2 = u & 8191;
        int col = u2 >> 5, v5 = u2 & 31, slot = v5 >> 3, e = v5 & 7;
        int kq = slot ^ ((col >> 1) & 3);
        int k = slab*32 + kq*8 + e;
        int rowz = gate*256 + col;
        v = (k < 73) ? W_ih[rowz*73 + k] : ((k < 96) ? 0.0f : W_hh[rowz*256 + (k-96)]);
    } else if (id < OFF_W2) {                // W1: 8 x 16KB kb-slabs
        int t = id - OFF_W1, kb = t >> 13, u2 = t & 8191;
        int col = u2 >> 5, v5 = u2 & 31, slot = v5 >> 3, e = v5 & 7;
        int kq = slot ^ ((col >> 1) & 3);
        v = W1[col*256 + kb*32 + kq*8 + e];
    } else if (id < OFF_W3) {                // W2: 8 x 8KB kb-slabs (128 cols)
        int t = id - OFF_W2, kb = t >> 12, u2 = t & 4095;
        int col = u2 >> 5, v5 = u2 & 31, slot = v5 >> 3, e = v5 & 7;
        int kq = slot ^ ((col >> 1) & 3);
        v = W2[col*256 + kb*32 + kq*8 + e];
    } else {                                 // W3: 4 x 16KB kb-slabs, cols>=162 zero
        int t = id - OFF_W3, kb = t >> 13, u2 = t & 8191;
        int col = u2 >> 5, v5 = u2 & 31, slot = v5 >> 3, e = v5 & 7;
        int kq = slot ^ ((col >> 1) & 3);
        int k = kb*32 + kq*8 + e;
        v = (col < 162) ? W3[col*128 + k] : 0.0f;
    }
    ws[id] = f2bf(v);
}

__global__ __launch_bounds__(NTHR, 1) void knet_mfma(
    const float* __restrict__ meas, const float* __restrict__ mask,
    const float* __restrict__ dt,   const float* __restrict__ baselines,
    const float* __restrict__ x_prev, const float* __restrict__ hx,
    const float* __restrict__ b_ih, const float* __restrict__ b_hh,
    const float* __restrict__ ln_g, const float* __restrict__ ln_b,
    const float* __restrict__ b1,   const float* __restrict__ b2,
    const float* __restrict__ b3,
    const ushort* __restrict__ ws,
    float* __restrict__ out)
{
    extern __shared__ char smem[];
    ushort* Rbu  = (ushort*)(smem + LDS_RBF2);   // Rb then F2
    char*   Hb   = smem + LDS_HB;
    char*   STG  = smem + LDS_STG;
    float*  xmc  = (float*)(smem + LDS_XMC);
    float*  lnscr= (float*)(smem + LDS_LNS);

    const int tid  = threadIdx.x;
    const int w    = __builtin_amdgcn_readfirstlane(tid >> 6);
    const int nq   = w & 3;
    const int mh   = w >> 2;
    const int lane = tid & 63;
    const int lr   = lane & 15;
    const int lk   = lane >> 4;
    const int lk8  = lk * 8;
    const int row0 = blockIdx.x * ROWS;
    const int mrow = mh*32 + lr;
    float* hout = out + (size_t)B_TOTAL*6;

    // prologue: slab 0 -> buf0 (linear copy)
    stage_lin<6>(ws + OFF_GRU, STG, w, lane);

    // ====== coalesced input staging -> buf1 scratch (f32) ======
    float* scr = (float*)(STG + 49152);
    {
        const size_t m0 = (size_t)row0*27;
        for (int i = tid; i < 1728; i += NTHR) scr[i]        = meas[m0 + i];
        for (int i = tid; i < 1728; i += NTHR) scr[1728 + i] = mask[m0 + i];
        const size_t b0 = (size_t)row0*12;
        for (int i = tid; i < 768; i += NTHR)  scr[3456 + i] = baselines[b0 + i];
        if (tid < 384) scr[4224 + tid] = x_prev[(size_t)row0*6 + tid];
        if (tid < 64)  scr[4608 + tid] = dt[row0 + tid];
        const size_t hbase = (size_t)row0 * 256;
        #pragma unroll
        for (int ii = 0; ii < 4; ++ii) {
            int cid = tid + ii*NTHR;
            int r  = cid >> 5;
            int k0 = (cid & 31) << 3;
            const float4* p = (const float4*)(hx + hbase + (size_t)r*256 + k0);
            float4 u = p[0], v2 = p[1];
            bf16x8 o;
            o[0]=(short)f2bf(u.x);  o[1]=(short)f2bf(u.y);  o[2]=(short)f2bf(u.z);  o[3]=(short)f2bf(u.w);
            o[4]=(short)f2bf(v2.x); o[5]=(short)f2bf(v2.y); o[6]=(short)f2bf(v2.z); o[7]=(short)f2bf(v2.w);
            *(bf16x8*)(Hb + swzb(r, k0)) = o;
        }
    }
    __syncthreads();

    // ====== geometry from scratch -> Rb, xmc ======
    if (w < 4) {
        const int row = lane;
        const float dtv = scr[4608 + row];
        const float dts = dtv * NORM_R;
        float xp[6], xm[6];
        #pragma unroll
        for (int s = 0; s < 6; ++s) xp[s] = scr[4224 + row*6 + s];
        xm[0] = xp[0] + dts*xp[1]; xm[1] = xp[1];
        xm[2] = xp[2] + dts*xp[3]; xm[3] = xp[3];
        xm[4] = xp[4] + dts*xp[5]; xm[5] = xp[5];
        if (w < 3) {
            float xr[6];
            #pragma unroll
            for (int s = 0; s < 6; ++s) {
                float b = (w == 0) ? 0.0f : scr[3456 + row*12 + (w-1)*6 + s];
                xr[s] = xm[s] - b;
            }
            float rxy = sqrtf(xr[0]*xr[0] + xr[2]*xr[2] + 1e-9f);
            float azv = atan2f(xr[2], xr[0]) * (1.0f/PI_F);
            float elv = atan2f(xr[4], rxy)   * (1.0f/PI_F);
            float rrv = sqrtf(xr[0]*xr[0] + xr[2]*xr[2] + xr[4]*xr[4] + 1e-9f);
            float y[9] = {azv, elv, rrv, azv, elv, 0.0f, azv, 0.0f, 0.0f};
            const bool ang[9] = {true,true,false,true,true,false,true,false,false};
            #pragma unroll
            for (int i = 0; i < 9; ++i) {
                int m = w*9 + i;
                float ms = scr[1728 + row*27 + m];
                float v  = scr[row*27 + m] - y[i];
                if (ang[i]) v = v - 2.0f*rintf(v*0.5f);
                v *= ms;
                Rbu[row*104 + m]      = f2bf(v);
                Rbu[row*104 + 27 + m] = f2bf(ms);
            }
        } else {
            Rbu[row*104 + 54] = f2bf(dtv);
            #pragma unroll
            for (int s = 0; s < 6; ++s) Rbu[row*104 + 55 + s] = f2bf(xm[s]);
            #pragma unroll
            for (int q = 0; q < 12; ++q) Rbu[row*104 + 61 + q] = f2bf(scr[3456 + row*12 + q]);
            #pragma unroll
            for (int k = 73; k < 96; ++k) Rbu[row*104 + k] = 0;
            #pragma unroll
            for (int s = 0; s < 6; ++s) xmc[row*6 + s] = xm[s];
        }
    }
    __syncthreads();

    // ====== GRU: 11 x 48KB phases (r,z,n per phase; shared A-frags) ======
    f32x4 ar[2][4], az[2][4], agi[2][4], agh[2][4];
    #pragma unroll
    for (int i = 0; i < 2; ++i)
        #pragma unroll
        for (int j = 0; j < 4; ++j) {
            ar[i][j]=(f32x4){0,0,0,0}; az[i][j]=(f32x4){0,0,0,0};
            agi[i][j]=(f32x4){0,0,0,0}; agh[i][j]=(f32x4){0,0,0,0};
        }
    #pragma unroll
    for (int kb = 0; kb < 11; ++kb) {
        WAIT_VM0; BARv;
        if (kb < 10) stage_lin<6>(ws + OFF_GRU + (kb+1)*GRU_SLAB, STG + ((kb+1)&1)*49152, w, lane);
        else         stage_lin<6>(ws + OFF_W1,                    STG + 49152,            w, lane); // p11 -> buf1
        const char* sb = STG + (kb&1)*49152;
        bf16x8 a0, a1;
        if (kb < 3) { a0 = *(const bf16x8*)(Rbu + mrow*104 + kb*32 + lk8);
                      a1 = *(const bf16x8*)(Rbu + (mrow+16)*104 + kb*32 + lk8); }
        else        { a0 = *(const bf16x8*)(Hb + swzb(mrow,    (kb-3)*32 + lk8));
                      a1 = *(const bf16x8*)(Hb + swzb(mrow+16, (kb-3)*32 + lk8)); }
        __builtin_amdgcn_s_setprio(1);
        mm4(sb,         nq*64, lr, lk, a0, a1, ar);
        mm4(sb + 16384, nq*64, lr, lk, a0, a1, az);
        if (kb < 3) mm4(sb + 32768, nq*64, lr, lk, a0, a1, agi);
        else        mm4(sb + 32768, nq*64, lr, lk, a0, a1, agh);
        __builtin_amdgcn_s_setprio(0);
    }

    // ====== GRU epilogue: gates -> h_new (regs) + global store + LN partials ======
    f32x4 hnv[2][4];
    float lsum[2] = {0,0}, lsq[2] = {0,0};
    #pragma unroll
    for (int j = 0; j < 4; ++j) {
        const int c0 = nq*64 + j*16 + lk*4;
        f32x4 bir = *(const f32x4*)(b_ih + c0),        bhr = *(const f32x4*)(b_hh + c0);
        f32x4 biz = *(const f32x4*)(b_ih + 256 + c0),  bhz = *(const f32x4*)(b_hh + 256 + c0);
        f32x4 bin_= *(const f32x4*)(b_ih + 512 + c0),  bhn = *(const f32x4*)(b_hh + 512 + c0);
        #pragma unroll
        for (int i = 0; i < 2; ++i) {
            const int row = mh*32 + i*16 + lr;
            uint2 hxd = *(const uint2*)(Hb + swzb(row, c0));
            float hx_[4] = { b2f((ushort)(hxd.x & 0xffffu)), b2f((ushort)(hxd.x >> 16)),
                             b2f((ushort)(hxd.y & 0xffffu)), b2f((ushort)(hxd.y >> 16)) };
            f32x4 hn4;
            #pragma unroll
            for (int e = 0; e < 4; ++e) {
                float rg = sigm(ar[i][j][e] + bir[e] + bhr[e]);
                float zg = sigm(az[i][j][e] + biz[e] + bhz[e]);
                float ng = tanh_(agi[i][j][e] + bin_[e] + rg*(agh[i][j][e] + bhn[e]));
                float hn = (1.0f - zg)*ng + zg*hx_[e];
                hn4[e] = hn;
                lsum[i] += hn; lsq[i] += hn*hn;
            }
            hnv[i][j] = hn4;
            float4 st = { hn4[0], hn4[1], hn4[2], hn4[3] };
            *(float4*)(hout + (size_t)(row0+row)*256 + c0) = st;
        }
    }
    #pragma unroll
    for (int i = 0; i < 2; ++i) {
        lsum[i] += __shfl_xor(lsum[i], 16); lsum[i] += __shfl_xor(lsum[i], 32);
        lsq[i]  += __shfl_xor(lsq[i], 16);  lsq[i]  += __shfl_xor(lsq[i], 32);
    }
    if (lk == 0) {
        #pragma unroll
        for (int i = 0; i < 2; ++i) {
            const int row = mh*32 + i*16 + lr;
            lnscr[row*8 + nq*2 + 0] = lsum[i];
            lnscr[row*8 + nq*2 + 1] = lsq[i];
        }
    }
    __syncthreads();

    // ====== LayerNorm apply (regs -> Hb h_ln) ======
    {
        float mu[2], rstd[2];
        #pragma unroll
        for (int i = 0; i < 2; ++i) {
            const int row = mh*32 + i*16 + lr;
            float s = 0, q = 0;
            #pragma unroll
            for (int qq = 0; qq < 4; ++qq) { s += lnscr[row*8 + qq*2]; q += lnscr[row*8 + qq*2 + 1]; }
            mu[i] = s * (1.0f/256.0f);
            rstd[i] = rsqrtf(q*(1.0f/256.0f) - mu[i]*mu[i] + 1e-5f);
        }
        #pragma unroll
        for (int j = 0; j < 4; ++j) {
            const int c0 = nq*64 + j*16 + lk*4;
            f32x4 g4 = *(const f32x4*)(ln_g + c0);
            f32x4 b4 = *(const f32x4*)(ln_b + c0);
            #pragma unroll
            for (int i = 0; i < 2; ++i) {
                const int row = mh*32 + i*16 + lr;
                float v0 = (hnv[i][j][0]-mu[i])*rstd[i]*g4[0] + b4[0];
                float v1 = (hnv[i][j][1]-mu[i])*rstd[i]*g4[1] + b4[1];
                float v2 = (hnv[i][j][2]-mu[i])*rstd[i]*g4[2] + b4[2];
                float v3 = (hnv[i][j][3]-mu[i])*rstd[i]*g4[3] + b4[3];
                uint2 o;
                o.x = (unsigned)f2bf(v0) | ((unsigned)f2bf(v1) << 16);
                o.y = (unsigned)f2bf(v2) | ((unsigned)f2bf(v3) << 16);
                *(uint2*)(Hb + swzb(row, c0)) = o;
            }
        }
    }
    __syncthreads();

    // ====== f1 = relu(W1 h_ln + b1): 3 phases (kb 0-2, 3-5, 6-7) ======
    f32x4 c2[2][4];
    #pragma unroll
    for (int i = 0; i < 2; ++i)
        #pragma unroll
        for (int j = 0; j < 4; ++j) c2[i][j] = (f32x4){0,0,0,0};
    // p11 (buf1): kb 0..2
    WAIT_VM0; BARv;
    stage_lin<6>(ws + OFF_W1 + 3*8192, STG, w, lane);            // p12 -> buf0
    {
        const char* sb = STG + 49152;
        #pragma unroll
        for (int kb = 0; kb < 3; ++kb) {
            bf16x8 a0 = *(const bf16x8*)(Hb + swzb(mrow,    kb*32 + lk8));
            bf16x8 a1 = *(const bf16x8*)(Hb + swzb(mrow+16, kb*32 + lk8));
            __builtin_amdgcn_s_setprio(1);
            mm4(sb + kb*16384, nq*64, lr, lk, a0, a1, c2);
            __builtin_amdgcn_s_setprio(0);
        }
    }
    // p12 (buf0): kb 3..5
    WAIT_VM0; BARv;
    stage_lin<4>(ws + OFF_W1 + 6*8192, STG + 49152, w, lane);    // p13 -> buf1
    {
        const char* sb = STG;
        #pragma unroll
        for (int kb = 3; kb < 6; ++kb) {
            bf16x8 a0 = *(const bf16x8*)(Hb + swzb(mrow,    kb*32 + lk8));
            bf16x8 a1 = *(const bf16x8*)(Hb + swzb(mrow+16, kb*32 + lk8));
            __builtin_amdgcn_s_setprio(1);
            mm4(sb + (kb-3)*16384, nq*64, lr, lk, a0, a1, c2);
            __builtin_amdgcn_s_setprio(0);
        }
    }
    // p13 (buf1): kb 6..7
    WAIT_VM0; BARv;
    stage_lin<4>(ws + OFF_W2, STG, w, lane);                     // p14 -> buf0
    {
        const char* sb = STG + 49152;
        #pragma unroll
        for (int kb = 6; kb < 8; ++kb) {
            bf16x8 a0 = *(const bf16x8*)(Hb + swzb(mrow,    kb*32 + lk8));
            bf16x8 a1 = *(const bf16x8*)(Hb + swzb(mrow+16, kb*32 + lk8));
            __builtin_amdgcn_s_setprio(1);
            mm4(sb + (kb-6)*16384, nq*64, lr, lk, a0, a1, c2);
            __builtin_amdgcn_s_setprio(0);
        }
    }
    __syncthreads();   // all h_ln reads done before f1-act overwrite of Hb
    #pragma unroll
    for (int j = 0; j < 4; ++j) {
        const int c0 = nq*64 + j*16 + lk*4;
        f32x4 b4 = *(const f32x4*)(b1 + c0);
        #pragma unroll
        for (int i = 0; i < 2; ++i) {
            const int row = mh*32 + i*16 + lr;
            uint2 o;
            o.x = (unsigned)f2bf(fmaxf(c2[i][j][0]+b4[0],0.f)) | ((unsigned)f2bf(fmaxf(c2[i][j][1]+b4[1],0.f)) << 16);
            o.y = (unsigned)f2bf(fmaxf(c2[i][j][2]+b4[2],0.f)) | ((unsigned)f2bf(fmaxf(c2[i][j][3]+b4[3],0.f)) << 16);
            *(uint2*)(Hb + swzb(row, c0)) = o;
        }
    }
    __syncthreads();

    // ====== f2 = relu(W2 f1 + b2): 2 phases ======
    f32x4 c3[2][2];
    #pragma unroll
    for (int i = 0; i < 2; ++i)
        #pragma unroll
        for (int j = 0; j < 2; ++j) c3[i][j] = (f32x4){0,0,0,0};
    // p14 (buf0): kb 0..3
    WAIT_VM0; BARv;
    stage_lin<4>(ws + OFF_W2 + 4*4096, STG + 49152, w, lane);    // p15 -> buf1
    {
        const char* sb = STG;
        #pragma unroll
        for (int kb = 0; kb < 4; ++kb) {
            bf16x8 a0 = *(const bf16x8*)(Hb + swzb(mrow,    kb*32 + lk8));
            bf16x8 a1 = *(const bf16x8*)(Hb + swzb(mrow+16, kb*32 + lk8));
            __builtin_amdgcn_s_setprio(1);
            #pragma unroll
            for (int j = 0; j < 2; ++j) {
                bf16x8 wf = rdW(sb + kb*8192, nq*32 + j*16 + lr, lk);
                c3[0][j] = __builtin_amdgcn_mfma_f32_16x16x32_bf16(wf, a0, c3[0][j], 0,0,0);
                c3[1][j] = __builtin_amdgcn_mfma_f32_16x16x32_bf16(wf, a1, c3[1][j], 0,0,0);
            }
            __builtin_amdgcn_s_setprio(0);
        }
    }
    // p15 (buf1): kb 4..7
    WAIT_VM0; BARv;
    stage_lin<4>(ws + OFF_W3, STG, w, lane);                     // p16 -> buf0
    {
        const char* sb = STG + 49152;
        #pragma unroll
        for (int kb = 4; kb < 8; ++kb) {
            bf16x8 a0 = *(const bf16x8*)(Hb + swzb(mrow,    kb*32 + lk8));
            bf16x8 a1 = *(const bf16x8*)(Hb + swzb(mrow+16, kb*32 + lk8));
            __builtin_amdgcn_s_setprio(1);
            #pragma unroll
            for (int j = 0; j < 2; ++j) {
                bf16x8 wf = rdW(sb + (kb-4)*8192, nq*32 + j*16 + lr, lk);
                c3[0][j] = __builtin_amdgcn_mfma_f32_16x16x32_bf16(wf, a0, c3[0][j], 0,0,0);
                c3[1][j] = __builtin_amdgcn_mfma_f32_16x16x32_bf16(wf, a1, c3[1][j], 0,0,0);
            }
            __builtin_amdgcn_s_setprio(0);
        }
    }
    // preload innov for einsum (Rb dies to F2 overlay next)
    f32x4 iv[2][3];
    #pragma unroll
    for (int j = 0; j < 3; ++j) {
        #pragma unroll
        for (int i = 0; i < 2; ++i) {
            const int row = mh*32 + i*16 + lr;
            #pragma unroll
            for (int e = 0; e < 4; ++e) {
                int col = nq*48 + j*16 + lk*4 + e;
                int m = col - 27*(col/27);
                iv[i][j][e] = b2f(Rbu[row*104 + m]);
            }
        }
    }
    __syncthreads();   // innov reads done before F2 writes over Rb
    #pragma unroll
    for (int j = 0; j < 2; ++j) {
        const int c0 = nq*32 + j*16 + lk*4;
        f32x4 b4 = *(const f32x4*)(b2 + c0);
        #pragma unroll
        for (int i = 0; i < 2; ++i) {
            const int row = mh*32 + i*16 + lr;
            uint2 o;
            o.x = (unsigned)f2bf(fmaxf(c3[i][j][0]+b4[0],0.f)) | ((unsigned)f2bf(fmaxf(c3[i][j][1]+b4[1],0.f)) << 16);
            o.y = (unsigned)f2bf(fmaxf(c3[i][j][2]+b4[2],0.f)) | ((unsigned)f2bf(fmaxf(c3[i][j][3]+b4[3],0.f)) << 16);
            *(uint2*)((char*)Rbu + row*272 + c0*2) = o;      // F2 [64][136] u16
        }
    }
    __syncthreads();

    // ====== K = clip(W3 f2 + b3): 2 phases + einsum ======
    f32x4 c4[2][3];
    #pragma unroll
    for (int i = 0; i < 2; ++i)
        #pragma unroll
        for (int j = 0; j < 3; ++j) c4[i][j] = (f32x4){0,0,0,0};
    // p16 (buf0): kb 0,1
    WAIT_VM0; BARv;
    stage_lin<4>(ws + OFF_W3 + 2*8192, STG + 49152, w, lane);    // p17 -> buf1
    {
        const char* sb = STG;
        #pragma unroll
        for (int kb = 0; kb < 2; ++kb) {
            bf16x8 a0 = *(const bf16x8*)((char*)Rbu + (mrow     )*272 + (kb*32 + lk8)*2);
            bf16x8 a1 = *(const bf16x8*)((char*)Rbu + (mrow + 16)*272 + (kb*32 + lk8)*2);
            __builtin_amdgcn_s_setprio(1);
            #pragma unroll
            for (int j = 0; j < 3; ++j) {
                bf16x8 wf = rdW(sb + kb*16384, nq*48 + j*16 + lr, lk);
                c4[0][j] = __builtin_amdgcn_mfma_f32_16x16x32_bf16(wf, a0, c4[0][j], 0,0,0);
                c4[1][j] = __builtin_amdgcn_mfma_f32_16x16x32_bf16(wf, a1, c4[1][j], 0,0,0);
            }
            __builtin_amdgcn_s_setprio(0);
        }
    }
    // p17 (buf1): kb 2,3
    WAIT_VM0; BARv;
    {
        const char* sb = STG + 49152;
        #pragma unroll
        for (int kb = 2; kb < 4; ++kb) {
            bf16x8 a0 = *(const bf16x8*)((char*)Rbu + (mrow     )*272 + (kb*32 + lk8)*2);
            bf16x8 a1 = *(const bf16x8*)((char*)Rbu + (mrow + 16)*272 + (kb*32 + lk8)*2);
            __builtin_amdgcn_s_setprio(1);
            #pragma unroll
            for (int j = 0; j < 3; ++j) {
                bf16x8 wf = rdW(sb + (kb-2)*16384, nq*48 + j*16 + lr, lk);
                c4[0][j] = __builtin_amdgcn_mfma_f32_16x16x32_bf16(wf, a0, c4[0][j], 0,0,0);
                c4[1][j] = __builtin_amdgcn_mfma_f32_16x16x32_bf16(wf, a1, c4[1][j], 0,0,0);
            }
            __builtin_amdgcn_s_setprio(0);
        }
    }
    #pragma unroll
    for (int j = 0; j < 3; ++j) {
        #pragma unroll
        for (int i = 0; i < 2; ++i) {
            const int row = mh*32 + i*16 + lr;
            #pragma unroll
            for (int e = 0; e < 4; ++e) {
                int col = nq*48 + j*16 + lk*4 + e;
                if (col < 162) {
                    int s = col / 27;
                    float K = fminf(fmaxf(c4[i][j][e] + b3[col], -3.0f), 3.0f);
                    atomicAdd(&xmc[row*6 + s], K * iv[i][j][e]);
                }
            }
        }
    }
    __syncthreads();

    for (int t = tid; t < ROWS*6; t += NTHR) {
        int row = t / 6, s = t - row*6;
        float v = fminf(fmaxf(xmc[t], -5.0f), 5.0f);
        out[(size_t)(row0+row)*6 + s] = v;
    }
}

extern "C" void kernel_launch(void* const* d_in, const int* in_sizes, int n_in,
                              void* d_out, int out_size, void* d_ws, size_t ws_size,
                              hipStream_t stream) {
    const float* meas      = (const float*)d_in[0];
    const float* mask      = (const float*)d_in[1];
    const float* dtv       = (const float*)d_in[2];
    const float* baselines = (const float*)d_in[3];
    const float* x_prev    = (const float*)d_in[4];
    const float* hx        = (const float*)d_in[5];
    const float* W_ih      = (const float*)d_in[6];
    const float* W_hh      = (const float*)d_in[7];
    const float* b_ih      = (const float*)d_in[8];
    const float* b_hh      = (const float*)d_in[9];
    const float* ln_g      = (const float*)d_in[10];
    const float* ln_b      = (const float*)d_in[11];
    const float* W1        = (const float*)d_in[12];
    const float* b1        = (const float*)d_in[13];
    const float* W2        = (const float*)d_in[14];
    const float* b2        = (const float*)d_in[15];
    const float* W3        = (const float*)d_in[16];
    const float* b3        = (const float*)d_in[17];
    ushort* wsb = (ushort*)d_ws;
    float* outp = (float*)d_out;

    prep_weights<<<(W_TOTAL + 255)/256, 256, 0, stream>>>(W_ih, W_hh, W1, W2, W3, wsb);
    knet_mfma<<<NWG, NTHR, LDS_TOTAL, stream>>>(
        meas, mask, dtv, baselines, x_prev, hx,
        b_ih, b_hh, ln_g, ln_b, b1, b2, b3, wsb, outp);
}